// Round 1
// baseline (279.927 us; speedup 1.0000x reference)
//
#include <hip/hip_runtime.h>

// Problem constants (fixed by the reference's setup_inputs).
#define BS    32
#define LEN   2048
#define DIM   512
#define NROWS (BS * LEN)          // 65536 rows total
#define NBLK  2048                // grid for the row kernel (8 blocks/CU)
#define NTHR  256                 // 4 waves/block
#define WPB   4                   // waves per block
#define NWAVE (NBLK * WPB)        // 8192 waves -> 8 rows per wave

// Kernel 1: one wave per row (grid-strided). Each lane loads 8 f32 of m1 and
// 8 f32 of m2 via coalesced float4 loads, computes partial sum / sum-of-squares,
// butterfly-reduces across the 64-lane wave, then every lane (identically)
// forms the per-row KL contribution. Per-block partial goes to d_ws.
__global__ __launch_bounds__(NTHR) void kl_rows(const float* __restrict__ m1,
                                                const float* __restrict__ m2,
                                                float* __restrict__ partials) {
    const int lane = threadIdx.x & 63;
    const int wid  = threadIdx.x >> 6;
    const int gw   = blockIdx.x * WPB + wid;

    double acc = 0.0;

    for (int r = gw; r < NROWS; r += NWAVE) {
        const float4* p1 = reinterpret_cast<const float4*>(m1 + (size_t)r * DIM);
        const float4* p2 = reinterpret_cast<const float4*>(m2 + (size_t)r * DIM);

        // Two fully-coalesced float4 loads per matrix:
        // load A covers elements [0,256), load B covers [256,512).
        float4 a0 = p1[lane];
        float4 a1 = p1[64 + lane];
        float4 b0 = p2[lane];
        float4 b1 = p2[64 + lane];

        float s1 = (a0.x + a0.y) + (a0.z + a0.w) + (a1.x + a1.y) + (a1.z + a1.w);
        float q1 = (a0.x * a0.x + a0.y * a0.y) + (a0.z * a0.z + a0.w * a0.w)
                 + (a1.x * a1.x + a1.y * a1.y) + (a1.z * a1.z + a1.w * a1.w);
        float s2 = (b0.x + b0.y) + (b0.z + b0.w) + (b1.x + b1.y) + (b1.z + b1.w);
        float q2 = (b0.x * b0.x + b0.y * b0.y) + (b0.z * b0.z + b0.w * b0.w)
                 + (b1.x * b1.x + b1.y * b1.y) + (b1.z * b1.z + b1.w * b1.w);

        // 64-lane butterfly reduction (wave = 64 on CDNA).
        #pragma unroll
        for (int off = 32; off; off >>= 1) {
            s1 += __shfl_xor(s1, off);
            q1 += __shfl_xor(q1, off);
            s2 += __shfl_xor(s2, off);
            q2 += __shfl_xor(q2, off);
        }

        // Unbiased variance: (sumsq - n*mean^2) / (n-1) == (q - s*mean)/(n-1).
        const float mean1 = s1 * (1.0f / DIM);
        const float mean2 = s2 * (1.0f / DIM);
        const float var1  = (q1 - s1 * mean1) * (1.0f / (DIM - 1));
        const float var2  = (q2 - s2 * mean2) * (1.0f / (DIM - 1));
        const float diff  = var2 - var1;

        // Per-row contribution: log(mean2)-log(mean1) + mean1/mean2 + diff^2/mean2
        const float c = (logf(mean2) - logf(mean1))
                      + (mean1 + diff * diff) / mean2;

        acc += (double)c;   // identical on all lanes after butterfly
    }

    __shared__ double sacc[WPB];
    if (lane == 0) sacc[wid] = acc;
    __syncthreads();
    if (threadIdx.x == 0) {
        double t = (sacc[0] + sacc[1]) + (sacc[2] + sacc[3]);
        partials[blockIdx.x] = (float)t;
    }
}

// Kernel 2: single block reduces the NBLK partials and applies the final
// affine transform: mean_over_bs(kl) = 0.5 * (total / BS - LEN).
__global__ __launch_bounds__(NTHR) void kl_final(const float* __restrict__ partials,
                                                 float* __restrict__ out) {
    double t = 0.0;
    for (int i = threadIdx.x; i < NBLK; i += NTHR) t += (double)partials[i];

    #pragma unroll
    for (int off = 32; off; off >>= 1) t += __shfl_xor(t, off);

    __shared__ double s[WPB];
    const int lane = threadIdx.x & 63;
    const int wid  = threadIdx.x >> 6;
    if (lane == 0) s[wid] = t;
    __syncthreads();
    if (threadIdx.x == 0) {
        double tot = (s[0] + s[1]) + (s[2] + s[3]);
        out[0] = (float)(0.5 * (tot / (double)BS - (double)LEN));
    }
}

extern "C" void kernel_launch(void* const* d_in, const int* in_sizes, int n_in,
                              void* d_out, int out_size, void* d_ws, size_t ws_size,
                              hipStream_t stream) {
    const float* m1 = (const float*)d_in[0];
    const float* m2 = (const float*)d_in[1];
    float* out      = (float*)d_out;
    float* partials = (float*)d_ws;   // NBLK floats = 8 KB scratch

    hipLaunchKernelGGL(kl_rows, dim3(NBLK), dim3(NTHR), 0, stream, m1, m2, partials);
    hipLaunchKernelGGL(kl_final, dim3(1), dim3(NTHR), 0, stream, partials, out);
}